// Round 5
// baseline (57.054 us; speedup 1.0000x reference)
//
#include <hip/hip_runtime.h>
#include <hip/hip_cooperative_groups.h>

namespace cg = cooperative_groups;

#define BATCH 256
#define NV    5000
#define NCLS  20000
#define G     4            // batch rows per block (interleaved by 4 in LDS)
#define NT    512          // threads per block (8 waves)
#define NCH   8            // clause chunks; grid = 64*8 = 512 = 2 blocks/CU
#define CCH   (NCLS / NCH) // 2500

// Horner over the 3 selector bits; f-deltas precomputed (shared across rows).
__device__ __forceinline__ float eval_c(float f0, float d0, float f2, float d1,
                                        float f4, float d2, float f6, float d3,
                                        float p0, float p1, float p2) {
    float t0 = fmaf(d0, p2, f0);
    float t1 = fmaf(d1, p2, f2);
    float t2 = fmaf(d2, p2, f4);
    float t3 = fmaf(d3, p2, f6);
    float u0 = fmaf(t1 - t0, p1, t0);
    float u1 = fmaf(t3 - t2, p1, t2);
    return fmaf(u1 - u0, p0, u0);
}

// Single cooperative dispatch: 512 blocks (bg = blk&63, cs = blk>>6).
// Phase 1: R2's main loop, partials -> ws. Grid sync. Phase 2: block 0 reduces.
__global__ __launch_bounds__(NT)
void bmn_fused(const float* __restrict__ x,
               const int*   __restrict__ vars,
               const float* __restrict__ factors,
               float* __restrict__ partial,
               float* __restrict__ out) {
    __shared__ float xs[NV * G];          // 80 KB: xs[v*4 + g] -> 2 blocks/CU exactly
    const int bg  = blockIdx.x & (BATCH / G - 1);
    const int cs  = blockIdx.x >> 6;
    const int tid = threadIdx.x;

    const float* xr = x + bg * G * NV;
    for (int i = tid; i < NV; i += NT) {
        float4 v;
        v.x = xr[i];
        v.y = xr[i + NV];
        v.z = xr[i + 2 * NV];
        v.w = xr[i + 3 * NV];
        *reinterpret_cast<float4*>(&xs[i * 4]) = v;   // consecutive b128: conflict-free
    }
    __syncthreads();

    float4 acc = make_float4(0.f, 0.f, 0.f, 0.f);
    const int cbase = cs * CCH;
    const int cend  = cbase + CCH;
    for (int c = cbase + tid; c < cend; c += NT) {
        const int v0 = vars[c * 3 + 0];
        const int v1 = vars[c * 3 + 1];
        const int v2 = vars[c * 3 + 2];
        const float4 fa = *reinterpret_cast<const float4*>(factors + c * 8);
        const float4 fb = *reinterpret_cast<const float4*>(factors + c * 8 + 4);
        const float4 p0 = *reinterpret_cast<const float4*>(&xs[v0 * 4]);
        const float4 p1 = *reinterpret_cast<const float4*>(&xs[v1 * 4]);
        const float4 p2 = *reinterpret_cast<const float4*>(&xs[v2 * 4]);
        const float d0 = fa.y - fa.x, d1 = fa.w - fa.z;
        const float d2 = fb.y - fb.x, d3 = fb.w - fb.z;
        acc.x += eval_c(fa.x, d0, fa.z, d1, fb.x, d2, fb.z, d3, p0.x, p1.x, p2.x);
        acc.y += eval_c(fa.x, d0, fa.z, d1, fb.x, d2, fb.z, d3, p0.y, p1.y, p2.y);
        acc.z += eval_c(fa.x, d0, fa.z, d1, fb.x, d2, fb.z, d3, p0.z, p1.z, p2.z);
        acc.w += eval_c(fa.x, d0, fa.z, d1, fb.x, d2, fb.z, d3, p0.w, p1.w, p2.w);
    }

    // wave reduce (64 lanes)
    for (int off = 32; off; off >>= 1) {
        acc.x += __shfl_down(acc.x, off, 64);
        acc.y += __shfl_down(acc.y, off, 64);
        acc.z += __shfl_down(acc.z, off, 64);
        acc.w += __shfl_down(acc.w, off, 64);
    }
    __shared__ float red[NT / 64][G];
    if ((tid & 63) == 0) {
        const int w = tid >> 6;
        red[w][0] = acc.x; red[w][1] = acc.y; red[w][2] = acc.z; red[w][3] = acc.w;
    }
    __syncthreads();
    if (tid < G) {
        float s = 0.f;
        #pragma unroll
        for (int w = 0; w < NT / 64; ++w) s += red[w][tid];
        partial[cs * BATCH + bg * G + tid] = s;
    }

    cg::this_grid().sync();

    // Phase 2: block 0 sums the 8 chunk-partials per batch row (coalesced in b).
    if (blockIdx.x == 0 && tid < BATCH) {
        float s = 0.f;
        #pragma unroll
        for (int k = 0; k < NCH; ++k) s += partial[k * BATCH + tid];
        out[tid] = s;
    }
}

// Fallback (ws too small): single chunk, direct write. Correct, slower.
__global__ __launch_bounds__(NT)
void bmn_direct(const float* __restrict__ x,
                const int*   __restrict__ vars,
                const float* __restrict__ factors,
                float* __restrict__ out) {
    __shared__ float xs[NV * G];
    const int bg  = blockIdx.x;
    const int tid = threadIdx.x;
    const float* xr = x + bg * G * NV;
    for (int i = tid; i < NV; i += NT) {
        float4 v;
        v.x = xr[i]; v.y = xr[i + NV]; v.z = xr[i + 2 * NV]; v.w = xr[i + 3 * NV];
        *reinterpret_cast<float4*>(&xs[i * 4]) = v;
    }
    __syncthreads();
    float4 acc = make_float4(0.f, 0.f, 0.f, 0.f);
    for (int c = tid; c < NCLS; c += NT) {
        const int v0 = vars[c * 3 + 0];
        const int v1 = vars[c * 3 + 1];
        const int v2 = vars[c * 3 + 2];
        const float4 fa = *reinterpret_cast<const float4*>(factors + c * 8);
        const float4 fb = *reinterpret_cast<const float4*>(factors + c * 8 + 4);
        const float4 p0 = *reinterpret_cast<const float4*>(&xs[v0 * 4]);
        const float4 p1 = *reinterpret_cast<const float4*>(&xs[v1 * 4]);
        const float4 p2 = *reinterpret_cast<const float4*>(&xs[v2 * 4]);
        const float d0 = fa.y - fa.x, d1 = fa.w - fa.z;
        const float d2 = fb.y - fb.x, d3 = fb.w - fb.z;
        acc.x += eval_c(fa.x, d0, fa.z, d1, fb.x, d2, fb.z, d3, p0.x, p1.x, p2.x);
        acc.y += eval_c(fa.x, d0, fa.z, d1, fb.x, d2, fb.z, d3, p0.y, p1.y, p2.y);
        acc.z += eval_c(fa.x, d0, fa.z, d1, fb.x, d2, fb.z, d3, p0.z, p1.z, p2.z);
        acc.w += eval_c(fa.x, d0, fa.z, d1, fb.x, d2, fb.z, d3, p0.w, p1.w, p2.w);
    }
    for (int off = 32; off; off >>= 1) {
        acc.x += __shfl_down(acc.x, off, 64);
        acc.y += __shfl_down(acc.y, off, 64);
        acc.z += __shfl_down(acc.z, off, 64);
        acc.w += __shfl_down(acc.w, off, 64);
    }
    __shared__ float red[NT / 64][G];
    if ((tid & 63) == 0) {
        const int w = tid >> 6;
        red[w][0] = acc.x; red[w][1] = acc.y; red[w][2] = acc.z; red[w][3] = acc.w;
    }
    __syncthreads();
    if (tid < G) {
        float s = 0.f;
        #pragma unroll
        for (int w = 0; w < NT / 64; ++w) s += red[w][tid];
        out[bg * G + tid] = s;
    }
}

extern "C" void kernel_launch(void* const* d_in, const int* in_sizes, int n_in,
                              void* d_out, int out_size, void* d_ws, size_t ws_size,
                              hipStream_t stream) {
    const float* x       = (const float*)d_in[0];
    // d_in[1] = binary_combinations (bit order hard-coded; verified rounds 1-4)
    const int*   vars    = (const int*)d_in[2];
    const float* factors = (const float*)d_in[3];
    float* out = (float*)d_out;

    if (ws_size >= (size_t)(NCH * BATCH) * sizeof(float)) {
        float* ws = (float*)d_ws;
        void* args[] = {(void*)&x, (void*)&vars, (void*)&factors, (void*)&ws, (void*)&out};
        hipLaunchCooperativeKernel((const void*)bmn_fused,
                                   dim3(NCH * BATCH / G), dim3(NT), args, 0, stream);
    } else {
        bmn_direct<<<dim3(BATCH / G), NT, 0, stream>>>(x, vars, factors, out);
    }
}